// Round 1
// baseline (718.985 us; speedup 1.0000x reference)
//
#include <hip/hip_runtime.h>
#include <hip/hip_bf16.h>
#include <stdint.h>

#define D_MODEL 2048
#define D_HIDDEN 8192
#define NTOK 8192
#define WELEMS (D_MODEL * D_HIDDEN)  // 16777216 (both w1 and w2)

typedef int v4i __attribute__((ext_vector_type(4)));
typedef _Float16 half8 __attribute__((ext_vector_type(8)));

// ---- workspace layout (bytes) ----
static const size_t OFF_QX  = 0;                                   // int8 [8192*2048]
static const size_t OFF_QW1 = OFF_QX  + (size_t)NTOK * D_MODEL;    // int8 [8192*2048]
static const size_t OFF_QW2 = OFF_QW1 + (size_t)WELEMS;            // int8 [2048*8192]
static const size_t OFF_QH  = OFF_QW2 + (size_t)WELEMS;            // int8 [8192*8192]
static const size_t OFF_H   = OFF_QH  + (size_t)NTOK * D_HIDDEN;   // fp16 [8192*8192]
static const size_t OFF_SXI = OFF_H   + (size_t)NTOK * D_HIDDEN * 2; // float[8192]
static const size_t OFF_SHI = OFF_SXI + (size_t)NTOK * 4;          // float[8192]
static const size_t OFF_WP  = OFF_SHI + (size_t)NTOK * 4;          // float[4]
static const size_t OFF_PART= OFF_WP  + 16;                        // double[2048]

// ---------- kernel 1: per-block partial sums of |w| (deterministic, fp64) ----------
__global__ void wabs_partial(const float* __restrict__ w1, const float* __restrict__ w2,
                             double* __restrict__ part) {
    const int b = blockIdx.x;
    const float* w = (b < 1024) ? w1 : w2;
    const int bb = (b < 1024) ? b : b - 1024;
    const float4* w4 = (const float4*)(w + (size_t)bb * 16384);
    double acc = 0.0;
    for (int i = threadIdx.x; i < 4096; i += 256) {
        float4 v = w4[i];
        acc += (double)fabsf(v.x) + (double)fabsf(v.y) + (double)fabsf(v.z) + (double)fabsf(v.w);
    }
    __shared__ double s[256];
    s[threadIdx.x] = acc;
    __syncthreads();
    for (int st = 128; st > 0; st >>= 1) {
        if (threadIdx.x < st) s[threadIdx.x] += s[threadIdx.x + st];
        __syncthreads();
    }
    if (threadIdx.x == 0) part[b] = s[0];
}

// ---------- kernel 2: finalize weight scales ----------
__global__ void wscale_final(const double* __restrict__ part, float* __restrict__ wpar) {
    __shared__ double s[1024];
    const int t = threadIdx.x;
    s[t] = part[t];
    __syncthreads();
    for (int st = 512; st > 0; st >>= 1) { if (t < st) s[t] += s[t + st]; __syncthreads(); }
    double sum1 = s[0];
    __syncthreads();
    s[t] = part[1024 + t];
    __syncthreads();
    for (int st = 512; st > 0; st >>= 1) { if (t < st) s[t] += s[t + st]; __syncthreads(); }
    double sum2 = s[0];
    if (t == 0) {
        float c1 = fmaxf((float)(sum1 / (double)WELEMS), 1e-5f);
        float c2 = fmaxf((float)(sum2 / (double)WELEMS), 1e-5f);
        float s1 = 1.0f / c1, s2 = 1.0f / c2;
        wpar[0] = s1; wpar[1] = 1.0f / s1;   // scale_w1, dequant_w1
        wpar[2] = s2; wpar[3] = 1.0f / s2;   // scale_w2, dequant_w2
    }
}

// ---------- kernel 3: ternary-quantize both weight matrices ----------
__global__ void quant_w(const float* __restrict__ w1, const float* __restrict__ w2,
                        const float* __restrict__ wpar,
                        int8_t* __restrict__ qw1, int8_t* __restrict__ qw2) {
    const size_t idx = (size_t)blockIdx.x * blockDim.x + threadIdx.x;  // 0..8388607
    const float* w; int8_t* q; float sc; size_t e;
    if (idx < (size_t)WELEMS / 4) { w = w1; q = qw1; sc = wpar[0]; e = idx * 4; }
    else                          { w = w2; q = qw2; sc = wpar[2]; e = (idx - WELEMS / 4) * 4; }
    float4 v = *(const float4*)(w + e);
    char4 o;
    o.x = (char)fminf(fmaxf(rintf(v.x * sc), -1.f), 1.f);
    o.y = (char)fminf(fmaxf(rintf(v.y * sc), -1.f), 1.f);
    o.z = (char)fminf(fmaxf(rintf(v.z * sc), -1.f), 1.f);
    o.w = (char)fminf(fmaxf(rintf(v.w * sc), -1.f), 1.f);
    *(char4*)(q + e) = o;
}

// ---------- kernel 4: per-token absmax quantize x ----------
__global__ void quant_x(const float* __restrict__ x, int8_t* __restrict__ qx,
                        float* __restrict__ sxinv) {
    const int row = blockIdx.x;
    const int t = threadIdx.x;
    const float4* x4 = (const float4*)(x + (size_t)row * D_MODEL);
    float4 a = x4[t * 2], b = x4[t * 2 + 1];
    float vals[8] = {a.x, a.y, a.z, a.w, b.x, b.y, b.z, b.w};
    float m = 0.f;
    #pragma unroll
    for (int i = 0; i < 8; ++i) m = fmaxf(m, fabsf(vals[i]));
    for (int off = 32; off > 0; off >>= 1) m = fmaxf(m, __shfl_xor(m, off, 64));
    __shared__ float s[4];
    if ((t & 63) == 0) s[t >> 6] = m;
    __syncthreads();
    m = fmaxf(fmaxf(s[0], s[1]), fmaxf(s[2], s[3]));
    const float clipv = fmaxf(m, 1e-5f);
    const float scale = 127.0f / clipv;
    if (t == 0) sxinv[row] = 1.0f / scale;
    union { char c[8]; int2 v; } u;
    #pragma unroll
    for (int i = 0; i < 8; ++i) {
        float qv = rintf(vals[i] * scale);
        qv = fminf(fmaxf(qv, -128.f), 127.f);
        u.c[i] = (char)qv;
    }
    *(int2*)(qx + (size_t)row * D_MODEL + t * 8) = u.v;
}

// ---------- kernel 6: per-token absmax quantize h (fp16 input) ----------
__global__ void quant_h(const _Float16* __restrict__ H, int8_t* __restrict__ qh,
                        float* __restrict__ shinv) {
    const int row = blockIdx.x;
    const int t = threadIdx.x;
    const half8* h8 = (const half8*)(H + (size_t)row * D_HIDDEN) + t * 4;
    half8 v0 = h8[0], v1 = h8[1], v2 = h8[2], v3 = h8[3];
    float vals[32];
    #pragma unroll
    for (int i = 0; i < 8; ++i) {
        vals[i]      = (float)v0[i];
        vals[i + 8]  = (float)v1[i];
        vals[i + 16] = (float)v2[i];
        vals[i + 24] = (float)v3[i];
    }
    float m = 0.f;
    #pragma unroll
    for (int i = 0; i < 32; ++i) m = fmaxf(m, fabsf(vals[i]));
    for (int off = 32; off > 0; off >>= 1) m = fmaxf(m, __shfl_xor(m, off, 64));
    __shared__ float s[4];
    if ((t & 63) == 0) s[t >> 6] = m;
    __syncthreads();
    m = fmaxf(fmaxf(s[0], s[1]), fmaxf(s[2], s[3]));
    const float clipv = fmaxf(m, 1e-5f);
    const float scale = 127.0f / clipv;
    if (t == 0) shinv[row] = 1.0f / scale;
    union { char c[16]; int4 v; } u0, u1;
    #pragma unroll
    for (int i = 0; i < 16; ++i) {
        float qa = rintf(vals[i] * scale);
        qa = fminf(fmaxf(qa, -128.f), 127.f);
        u0.c[i] = (char)qa;
        float qb = rintf(vals[16 + i] * scale);
        qb = fminf(fmaxf(qb, -128.f), 127.f);
        u1.c[i] = (char)qb;
    }
    int4* dst = (int4*)(qh + (size_t)row * D_HIDDEN + t * 32);
    dst[0] = u0.v;
    dst[1] = u1.v;
}

// ---------- int8 MFMA GEMM: C[M,N] = A[M,K] * B[N,K]^T (both K-contiguous) ----------
// MODE 0: dequant + exact-erf GELU -> fp16 H ; MODE 1: dequant -> fp32 out
template <int MODE>
__global__ __launch_bounds__(256) void gemm_i8(
    const int8_t* __restrict__ A, const int8_t* __restrict__ B,
    void* __restrict__ Cout, const float* __restrict__ rowinv,
    const float* __restrict__ wdeq, int K, int N) {
    __shared__ __align__(16) int8_t As[128 * 64];
    __shared__ __align__(16) int8_t Bs[128 * 64];
    const int tid = threadIdx.x;
    const int lane = tid & 63;
    const int wid = tid >> 6;
    const int row0 = blockIdx.y * 128;
    const int col0 = blockIdx.x * 128;
    const int wm = (wid >> 1) * 64;
    const int wn = (wid & 1) * 64;
    const int r = lane & 15;
    const int q = lane >> 4;
    v4i acc[4][4] = {};

    for (int k0 = 0; k0 < K; k0 += 64) {
        __syncthreads();
        #pragma unroll
        for (int it = 0; it < 2; ++it) {
            const int o = tid * 16 + it * 4096;
            const int m = o >> 6;
            const int kk = o & 63;
            __builtin_amdgcn_global_load_lds(
                (const __attribute__((address_space(1))) void*)(A + (size_t)(row0 + m) * K + (k0 + kk)),
                (__attribute__((address_space(3))) void*)(As + o), 16, 0, 0);
            __builtin_amdgcn_global_load_lds(
                (const __attribute__((address_space(1))) void*)(B + (size_t)(col0 + m) * K + (k0 + kk)),
                (__attribute__((address_space(3))) void*)(Bs + o), 16, 0, 0);
        }
        __syncthreads();
        v4i af[4], bf[4];
        #pragma unroll
        for (int i = 0; i < 4; ++i)
            af[i] = *(const v4i*)(As + (wm + i * 16 + r) * 64 + q * 16);
        #pragma unroll
        for (int i = 0; i < 4; ++i)
            bf[i] = *(const v4i*)(Bs + (wn + i * 16 + r) * 64 + q * 16);
        #pragma unroll
        for (int mi = 0; mi < 4; ++mi)
            #pragma unroll
            for (int ni = 0; ni < 4; ++ni)
                acc[mi][ni] = __builtin_amdgcn_mfma_i32_16x16x64_i8(af[mi], bf[ni], acc[mi][ni], 0, 0, 0);
    }

    const float dw = *wdeq;
    #pragma unroll
    for (int mi = 0; mi < 4; ++mi) {
        #pragma unroll
        for (int rr = 0; rr < 4; ++rr) {
            const int grow = row0 + wm + mi * 16 + q * 4 + rr;
            const float ri = rowinv[grow] * dw;
            #pragma unroll
            for (int ni = 0; ni < 4; ++ni) {
                const int gcol = col0 + wn + ni * 16 + r;
                float v = (float)acc[mi][ni][rr] * ri;
                if (MODE == 0) {
                    float g = 0.5f * v * (1.0f + erff(v * 0.70710678118654752f));
                    ((_Float16*)Cout)[(size_t)grow * N + gcol] = (_Float16)g;
                } else {
                    ((float*)Cout)[(size_t)grow * N + gcol] = v;
                }
            }
        }
    }
}

extern "C" void kernel_launch(void* const* d_in, const int* in_sizes, int n_in,
                              void* d_out, int out_size, void* d_ws, size_t ws_size,
                              hipStream_t stream) {
    const float* x  = (const float*)d_in[0];
    const float* w1 = (const float*)d_in[1];
    const float* w2 = (const float*)d_in[2];
    float* out = (float*)d_out;
    char* ws = (char*)d_ws;

    int8_t*   qx   = (int8_t*)(ws + OFF_QX);
    int8_t*   qw1  = (int8_t*)(ws + OFF_QW1);
    int8_t*   qw2  = (int8_t*)(ws + OFF_QW2);
    int8_t*   qh   = (int8_t*)(ws + OFF_QH);
    _Float16* h    = (_Float16*)(ws + OFF_H);
    float*    sxi  = (float*)(ws + OFF_SXI);
    float*    shi  = (float*)(ws + OFF_SHI);
    float*    wpar = (float*)(ws + OFF_WP);
    double*   part = (double*)(ws + OFF_PART);

    wabs_partial<<<2048, 256, 0, stream>>>(w1, w2, part);
    wscale_final<<<1, 1024, 0, stream>>>(part, wpar);
    quant_w<<<32768, 256, 0, stream>>>(w1, w2, wpar, qw1, qw2);
    quant_x<<<NTOK, 256, 0, stream>>>(x, qx, sxi);
    gemm_i8<0><<<dim3(D_HIDDEN / 128, NTOK / 128), 256, 0, stream>>>(
        qx, qw1, (void*)h, sxi, wpar + 1, D_MODEL, D_HIDDEN);
    quant_h<<<NTOK, 256, 0, stream>>>(h, qh, shi);
    gemm_i8<1><<<dim3(D_MODEL / 128, NTOK / 128), 256, 0, stream>>>(
        qh, qw2, (void*)out, shi, wpar + 3, D_HIDDEN, D_MODEL);
}

// Round 2
// 669.113 us; speedup vs baseline: 1.0745x; 1.0745x over previous
//
#include <hip/hip_runtime.h>
#include <hip/hip_bf16.h>
#include <stdint.h>

#define D_MODEL 2048
#define D_HIDDEN 8192
#define NTOK 8192
#define WELEMS (D_MODEL * D_HIDDEN)  // 16777216 (both w1 and w2)

typedef int v4i __attribute__((ext_vector_type(4)));
typedef _Float16 half8 __attribute__((ext_vector_type(8)));

// ---- workspace layout (bytes) ----
static const size_t OFF_QX  = 0;                                   // int8 [8192*2048]
static const size_t OFF_QW1 = OFF_QX  + (size_t)NTOK * D_MODEL;    // int8 [8192*2048]
static const size_t OFF_QW2 = OFF_QW1 + (size_t)WELEMS;            // int8 [2048*8192]
static const size_t OFF_QH  = OFF_QW2 + (size_t)WELEMS;            // int8 [8192*8192]
static const size_t OFF_H   = OFF_QH  + (size_t)NTOK * D_HIDDEN;   // fp16 [8192*8192]
static const size_t OFF_SXI = OFF_H   + (size_t)NTOK * D_HIDDEN * 2; // float[8192]
static const size_t OFF_SHI = OFF_SXI + (size_t)NTOK * 4;          // float[8192]
static const size_t OFF_WP  = OFF_SHI + (size_t)NTOK * 4;          // float[4]
static const size_t OFF_PART= OFF_WP  + 16;                        // double[2048]

// ---------- kernel 1: per-block partial sums of |w| (deterministic, fp64) ----------
__global__ void wabs_partial(const float* __restrict__ w1, const float* __restrict__ w2,
                             double* __restrict__ part) {
    const int b = blockIdx.x;
    const float* w = (b < 1024) ? w1 : w2;
    const int bb = (b < 1024) ? b : b - 1024;
    const float4* w4 = (const float4*)(w + (size_t)bb * 16384);
    double acc = 0.0;
    for (int i = threadIdx.x; i < 4096; i += 256) {
        float4 v = w4[i];
        acc += (double)fabsf(v.x) + (double)fabsf(v.y) + (double)fabsf(v.z) + (double)fabsf(v.w);
    }
    __shared__ double s[256];
    s[threadIdx.x] = acc;
    __syncthreads();
    for (int st = 128; st > 0; st >>= 1) {
        if (threadIdx.x < st) s[threadIdx.x] += s[threadIdx.x + st];
        __syncthreads();
    }
    if (threadIdx.x == 0) part[b] = s[0];
}

// ---------- kernel 2: finalize weight scales ----------
__global__ void wscale_final(const double* __restrict__ part, float* __restrict__ wpar) {
    __shared__ double s[1024];
    const int t = threadIdx.x;
    s[t] = part[t];
    __syncthreads();
    for (int st = 512; st > 0; st >>= 1) { if (t < st) s[t] += s[t + st]; __syncthreads(); }
    double sum1 = s[0];
    __syncthreads();
    s[t] = part[1024 + t];
    __syncthreads();
    for (int st = 512; st > 0; st >>= 1) { if (t < st) s[t] += s[t + st]; __syncthreads(); }
    double sum2 = s[0];
    if (t == 0) {
        float c1 = fmaxf((float)(sum1 / (double)WELEMS), 1e-5f);
        float c2 = fmaxf((float)(sum2 / (double)WELEMS), 1e-5f);
        float s1 = 1.0f / c1, s2 = 1.0f / c2;
        wpar[0] = s1; wpar[1] = 1.0f / s1;   // scale_w1, dequant_w1
        wpar[2] = s2; wpar[3] = 1.0f / s2;   // scale_w2, dequant_w2
    }
}

// ---------- kernel 3: ternary-quantize both weight matrices ----------
__global__ void quant_w(const float* __restrict__ w1, const float* __restrict__ w2,
                        const float* __restrict__ wpar,
                        int8_t* __restrict__ qw1, int8_t* __restrict__ qw2) {
    const size_t idx = (size_t)blockIdx.x * blockDim.x + threadIdx.x;  // 0..8388607
    const float* w; int8_t* q; float sc; size_t e;
    if (idx < (size_t)WELEMS / 4) { w = w1; q = qw1; sc = wpar[0]; e = idx * 4; }
    else                          { w = w2; q = qw2; sc = wpar[2]; e = (idx - WELEMS / 4) * 4; }
    float4 v = *(const float4*)(w + e);
    char4 o;
    o.x = (char)fminf(fmaxf(rintf(v.x * sc), -1.f), 1.f);
    o.y = (char)fminf(fmaxf(rintf(v.y * sc), -1.f), 1.f);
    o.z = (char)fminf(fmaxf(rintf(v.z * sc), -1.f), 1.f);
    o.w = (char)fminf(fmaxf(rintf(v.w * sc), -1.f), 1.f);
    *(char4*)(q + e) = o;
}

// ---------- kernel 4: per-token absmax quantize x ----------
__global__ void quant_x(const float* __restrict__ x, int8_t* __restrict__ qx,
                        float* __restrict__ sxinv) {
    const int row = blockIdx.x;
    const int t = threadIdx.x;
    const float4* x4 = (const float4*)(x + (size_t)row * D_MODEL);
    float4 a = x4[t * 2], b = x4[t * 2 + 1];
    float vals[8] = {a.x, a.y, a.z, a.w, b.x, b.y, b.z, b.w};
    float m = 0.f;
    #pragma unroll
    for (int i = 0; i < 8; ++i) m = fmaxf(m, fabsf(vals[i]));
    for (int off = 32; off > 0; off >>= 1) m = fmaxf(m, __shfl_xor(m, off, 64));
    __shared__ float s[4];
    if ((t & 63) == 0) s[t >> 6] = m;
    __syncthreads();
    m = fmaxf(fmaxf(s[0], s[1]), fmaxf(s[2], s[3]));
    const float clipv = fmaxf(m, 1e-5f);
    const float scale = 127.0f / clipv;
    if (t == 0) sxinv[row] = 1.0f / scale;
    union { char c[8]; int2 v; } u;
    #pragma unroll
    for (int i = 0; i < 8; ++i) {
        float qv = rintf(vals[i] * scale);
        qv = fminf(fmaxf(qv, -128.f), 127.f);
        u.c[i] = (char)qv;
    }
    *(int2*)(qx + (size_t)row * D_MODEL + t * 8) = u.v;
}

// ---------- kernel 6: per-token absmax quantize h (fp16 input) ----------
__global__ void quant_h(const _Float16* __restrict__ H, int8_t* __restrict__ qh,
                        float* __restrict__ shinv) {
    const int row = blockIdx.x;
    const int t = threadIdx.x;
    const half8* h8 = (const half8*)(H + (size_t)row * D_HIDDEN) + t * 4;
    half8 v0 = h8[0], v1 = h8[1], v2 = h8[2], v3 = h8[3];
    float vals[32];
    #pragma unroll
    for (int i = 0; i < 8; ++i) {
        vals[i]      = (float)v0[i];
        vals[i + 8]  = (float)v1[i];
        vals[i + 16] = (float)v2[i];
        vals[i + 24] = (float)v3[i];
    }
    float m = 0.f;
    #pragma unroll
    for (int i = 0; i < 32; ++i) m = fmaxf(m, fabsf(vals[i]));
    for (int off = 32; off > 0; off >>= 1) m = fmaxf(m, __shfl_xor(m, off, 64));
    __shared__ float s[4];
    if ((t & 63) == 0) s[t >> 6] = m;
    __syncthreads();
    m = fmaxf(fmaxf(s[0], s[1]), fmaxf(s[2], s[3]));
    const float clipv = fmaxf(m, 1e-5f);
    const float scale = 127.0f / clipv;
    if (t == 0) shinv[row] = 1.0f / scale;
    union { char c[16]; int4 v; } u0, u1;
    #pragma unroll
    for (int i = 0; i < 16; ++i) {
        float qa = rintf(vals[i] * scale);
        qa = fminf(fmaxf(qa, -128.f), 127.f);
        u0.c[i] = (char)qa;
        float qb = rintf(vals[16 + i] * scale);
        qb = fminf(fmaxf(qb, -128.f), 127.f);
        u1.c[i] = (char)qb;
    }
    int4* dst = (int4*)(qh + (size_t)row * D_HIDDEN + t * 32);
    dst[0] = u0.v;
    dst[1] = u1.v;
}

// ---------- int8 MFMA GEMM: C[M,N] = A[M,K] * B[N,K]^T (both K-contiguous) ----------
// Double-buffered LDS, ONE barrier per 64-K step, XOR-swizzled LDS chunks.
// LDS chunk layout: slot (row, cphys) holds global chunk cphys ^ ((row>>2)&3),
// applied on the GLOBAL address (global_load_lds LDS dest must stay lane-linear).
// MODE 0: dequant + exact-erf GELU -> fp16 H ; MODE 1: dequant -> fp32 out
template <int MODE>
__global__ __launch_bounds__(256) void gemm_i8(
    const int8_t* __restrict__ A, const int8_t* __restrict__ B,
    void* __restrict__ Cout, const float* __restrict__ rowinv,
    const float* __restrict__ wdeq, int K, int N) {
    __shared__ __align__(16) int8_t As[2][128 * 64];
    __shared__ __align__(16) int8_t Bs[2][128 * 64];
    const int tid = threadIdx.x;
    const int lane = tid & 63;
    const int wid = tid >> 6;
    const int row0 = blockIdx.y * 128;
    const int col0 = blockIdx.x * 128;
    const int wm = (wid >> 1) * 64;
    const int wn = (wid & 1) * 64;
    const int r = lane & 15;
    const int q = lane >> 4;

    // staging addresses: thread tid loads 16B chunk -> LDS offset tid*16 (+4096)
    const int sm = tid >> 2;       // LDS row 0..63 (it0), +64 (it1)
    const int sc = tid & 3;        // physical chunk column
    const int swk = ((sc ^ ((sm >> 2) & 3)) << 4);  // swizzled k-offset within row
    const int8_t* gA0 = A + (size_t)(row0 + sm) * K + swk;
    const int8_t* gA1 = gA0 + (size_t)64 * K;
    const int8_t* gB0 = B + (size_t)(col0 + sm) * K + swk;
    const int8_t* gB1 = gB0 + (size_t)64 * K;
    const int ldso = tid * 16;

#define STAGE(pA, pB, kk)                                                              \
    do {                                                                               \
        __builtin_amdgcn_global_load_lds(                                              \
            (const __attribute__((address_space(1))) void*)(gA0 + (kk)),               \
            (__attribute__((address_space(3))) void*)((pA) + ldso), 16, 0, 0);         \
        __builtin_amdgcn_global_load_lds(                                              \
            (const __attribute__((address_space(1))) void*)(gA1 + (kk)),               \
            (__attribute__((address_space(3))) void*)((pA) + ldso + 4096), 16, 0, 0);  \
        __builtin_amdgcn_global_load_lds(                                              \
            (const __attribute__((address_space(1))) void*)(gB0 + (kk)),               \
            (__attribute__((address_space(3))) void*)((pB) + ldso), 16, 0, 0);         \
        __builtin_amdgcn_global_load_lds(                                              \
            (const __attribute__((address_space(1))) void*)(gB1 + (kk)),               \
            (__attribute__((address_space(3))) void*)((pB) + ldso + 4096), 16, 0, 0);  \
    } while (0)

    // per-thread swizzled LDS read offsets for fragments
    int aoff[4], boff[4];
    const int rchunk = (q ^ (r >> 2)) << 4;
    #pragma unroll
    for (int i = 0; i < 4; ++i) {
        aoff[i] = (wm + i * 16 + r) * 64 + rchunk;
        boff[i] = (wn + i * 16 + r) * 64 + rchunk;
    }

    v4i acc[4][4] = {};

#define COMPUTE(pA, pB)                                                                 \
    do {                                                                                \
        v4i af[4], bf[4];                                                               \
        _Pragma("unroll") for (int i = 0; i < 4; ++i) {                                 \
            af[i] = *(const v4i*)((pA) + aoff[i]);                                      \
            bf[i] = *(const v4i*)((pB) + boff[i]);                                      \
        }                                                                               \
        _Pragma("unroll") for (int mi = 0; mi < 4; ++mi)                                \
            _Pragma("unroll") for (int ni = 0; ni < 4; ++ni)                            \
                acc[mi][ni] =                                                           \
                    __builtin_amdgcn_mfma_i32_16x16x64_i8(af[mi], bf[ni], acc[mi][ni],  \
                                                          0, 0, 0);                     \
    } while (0)

    STAGE(As[0], Bs[0], 0);
    for (int k0 = 0; k0 < K; k0 += 128) {
        __syncthreads();                               // drains tile k0 loads
        if (k0 + 64 < K) STAGE(As[1], Bs[1], k0 + 64); // prefetch next, hidden by compute
        COMPUTE(As[0], Bs[0]);
        __syncthreads();                               // drains tile k0+64 loads
        if (k0 + 128 < K) STAGE(As[0], Bs[0], k0 + 128);
        COMPUTE(As[1], Bs[1]);
    }
#undef STAGE
#undef COMPUTE

    const float dw = *wdeq;
    #pragma unroll
    for (int mi = 0; mi < 4; ++mi) {
        #pragma unroll
        for (int rr = 0; rr < 4; ++rr) {
            const int grow = row0 + wm + mi * 16 + q * 4 + rr;
            const float ri = rowinv[grow] * dw;
            #pragma unroll
            for (int ni = 0; ni < 4; ++ni) {
                const int gcol = col0 + wn + ni * 16 + r;
                float v = (float)acc[mi][ni][rr] * ri;
                if (MODE == 0) {
                    float g = 0.5f * v * (1.0f + erff(v * 0.70710678118654752f));
                    ((_Float16*)Cout)[(size_t)grow * N + gcol] = (_Float16)g;
                } else {
                    ((float*)Cout)[(size_t)grow * N + gcol] = v;
                }
            }
        }
    }
}

extern "C" void kernel_launch(void* const* d_in, const int* in_sizes, int n_in,
                              void* d_out, int out_size, void* d_ws, size_t ws_size,
                              hipStream_t stream) {
    const float* x  = (const float*)d_in[0];
    const float* w1 = (const float*)d_in[1];
    const float* w2 = (const float*)d_in[2];
    float* out = (float*)d_out;
    char* ws = (char*)d_ws;

    int8_t*   qx   = (int8_t*)(ws + OFF_QX);
    int8_t*   qw1  = (int8_t*)(ws + OFF_QW1);
    int8_t*   qw2  = (int8_t*)(ws + OFF_QW2);
    int8_t*   qh   = (int8_t*)(ws + OFF_QH);
    _Float16* h    = (_Float16*)(ws + OFF_H);
    float*    sxi  = (float*)(ws + OFF_SXI);
    float*    shi  = (float*)(ws + OFF_SHI);
    float*    wpar = (float*)(ws + OFF_WP);
    double*   part = (double*)(ws + OFF_PART);

    wabs_partial<<<2048, 256, 0, stream>>>(w1, w2, part);
    wscale_final<<<1, 1024, 0, stream>>>(part, wpar);
    quant_w<<<32768, 256, 0, stream>>>(w1, w2, wpar, qw1, qw2);
    quant_x<<<NTOK, 256, 0, stream>>>(x, qx, sxi);
    gemm_i8<0><<<dim3(D_HIDDEN / 128, NTOK / 128), 256, 0, stream>>>(
        qx, qw1, (void*)h, sxi, wpar + 1, D_MODEL, D_HIDDEN);
    quant_h<<<NTOK, 256, 0, stream>>>(h, qh, shi);
    gemm_i8<1><<<dim3(D_MODEL / 128, NTOK / 128), 256, 0, stream>>>(
        qh, qw2, (void*)out, shi, wpar + 3, D_HIDDEN, D_MODEL);
}

// Round 3
// 623.449 us; speedup vs baseline: 1.1532x; 1.0732x over previous
//
#include <hip/hip_runtime.h>
#include <hip/hip_bf16.h>
#include <stdint.h>

#define D_MODEL 2048
#define D_HIDDEN 8192
#define NTOK 8192
#define WELEMS (D_MODEL * D_HIDDEN)  // 16777216 (both w1 and w2)

typedef int v4i __attribute__((ext_vector_type(4)));
typedef int v16i __attribute__((ext_vector_type(16)));
typedef _Float16 half8 __attribute__((ext_vector_type(8)));

// ---- workspace layout (bytes) ----
static const size_t OFF_QX  = 0;                                   // int8 [8192*2048]
static const size_t OFF_QW1 = OFF_QX  + (size_t)NTOK * D_MODEL;    // int8 [8192*2048]
static const size_t OFF_QW2 = OFF_QW1 + (size_t)WELEMS;            // int8 [2048*8192]
static const size_t OFF_QH  = OFF_QW2 + (size_t)WELEMS;            // int8 [8192*8192]
static const size_t OFF_H   = OFF_QH  + (size_t)NTOK * D_HIDDEN;   // fp16 [8192*8192]
static const size_t OFF_SXI = OFF_H   + (size_t)NTOK * D_HIDDEN * 2; // float[8192]
static const size_t OFF_SHI = OFF_SXI + (size_t)NTOK * 4;          // float[8192]
static const size_t OFF_WP  = OFF_SHI + (size_t)NTOK * 4;          // float[4]
static const size_t OFF_PART= OFF_WP  + 16;                        // double[2048]

// ---------- kernel 1: per-block partial sums of |w| (deterministic, fp64) ----------
__global__ void wabs_partial(const float* __restrict__ w1, const float* __restrict__ w2,
                             double* __restrict__ part) {
    const int b = blockIdx.x;
    const float* w = (b < 1024) ? w1 : w2;
    const int bb = (b < 1024) ? b : b - 1024;
    const float4* w4 = (const float4*)(w + (size_t)bb * 16384);
    double acc = 0.0;
    for (int i = threadIdx.x; i < 4096; i += 256) {
        float4 v = w4[i];
        acc += (double)fabsf(v.x) + (double)fabsf(v.y) + (double)fabsf(v.z) + (double)fabsf(v.w);
    }
    __shared__ double s[256];
    s[threadIdx.x] = acc;
    __syncthreads();
    for (int st = 128; st > 0; st >>= 1) {
        if (threadIdx.x < st) s[threadIdx.x] += s[threadIdx.x + st];
        __syncthreads();
    }
    if (threadIdx.x == 0) part[b] = s[0];
}

// ---------- kernel 2: finalize weight scales ----------
__global__ void wscale_final(const double* __restrict__ part, float* __restrict__ wpar) {
    __shared__ double s[1024];
    const int t = threadIdx.x;
    s[t] = part[t];
    __syncthreads();
    for (int st = 512; st > 0; st >>= 1) { if (t < st) s[t] += s[t + st]; __syncthreads(); }
    double sum1 = s[0];
    __syncthreads();
    s[t] = part[1024 + t];
    __syncthreads();
    for (int st = 512; st > 0; st >>= 1) { if (t < st) s[t] += s[t + st]; __syncthreads(); }
    double sum2 = s[0];
    if (t == 0) {
        float c1 = fmaxf((float)(sum1 / (double)WELEMS), 1e-5f);
        float c2 = fmaxf((float)(sum2 / (double)WELEMS), 1e-5f);
        float s1 = 1.0f / c1, s2 = 1.0f / c2;
        wpar[0] = s1; wpar[1] = 1.0f / s1;   // scale_w1, dequant_w1
        wpar[2] = s2; wpar[3] = 1.0f / s2;   // scale_w2, dequant_w2
    }
}

// ---------- kernel 3: ternary-quantize both weight matrices ----------
__global__ void quant_w(const float* __restrict__ w1, const float* __restrict__ w2,
                        const float* __restrict__ wpar,
                        int8_t* __restrict__ qw1, int8_t* __restrict__ qw2) {
    const size_t idx = (size_t)blockIdx.x * blockDim.x + threadIdx.x;  // 0..8388607
    const float* w; int8_t* q; float sc; size_t e;
    if (idx < (size_t)WELEMS / 4) { w = w1; q = qw1; sc = wpar[0]; e = idx * 4; }
    else                          { w = w2; q = qw2; sc = wpar[2]; e = (idx - WELEMS / 4) * 4; }
    float4 v = *(const float4*)(w + e);
    char4 o;
    o.x = (char)fminf(fmaxf(rintf(v.x * sc), -1.f), 1.f);
    o.y = (char)fminf(fmaxf(rintf(v.y * sc), -1.f), 1.f);
    o.z = (char)fminf(fmaxf(rintf(v.z * sc), -1.f), 1.f);
    o.w = (char)fminf(fmaxf(rintf(v.w * sc), -1.f), 1.f);
    *(char4*)(q + e) = o;
}

// ---------- kernel 4: per-token absmax quantize x ----------
__global__ void quant_x(const float* __restrict__ x, int8_t* __restrict__ qx,
                        float* __restrict__ sxinv) {
    const int row = blockIdx.x;
    const int t = threadIdx.x;
    const float4* x4 = (const float4*)(x + (size_t)row * D_MODEL);
    float4 a = x4[t * 2], b = x4[t * 2 + 1];
    float vals[8] = {a.x, a.y, a.z, a.w, b.x, b.y, b.z, b.w};
    float m = 0.f;
    #pragma unroll
    for (int i = 0; i < 8; ++i) m = fmaxf(m, fabsf(vals[i]));
    for (int off = 32; off > 0; off >>= 1) m = fmaxf(m, __shfl_xor(m, off, 64));
    __shared__ float s[4];
    if ((t & 63) == 0) s[t >> 6] = m;
    __syncthreads();
    m = fmaxf(fmaxf(s[0], s[1]), fmaxf(s[2], s[3]));
    const float clipv = fmaxf(m, 1e-5f);
    const float scale = 127.0f / clipv;
    if (t == 0) sxinv[row] = 1.0f / scale;
    union { char c[8]; int2 v; } u;
    #pragma unroll
    for (int i = 0; i < 8; ++i) {
        float qv = rintf(vals[i] * scale);
        qv = fminf(fmaxf(qv, -128.f), 127.f);
        u.c[i] = (char)qv;
    }
    *(int2*)(qx + (size_t)row * D_MODEL + t * 8) = u.v;
}

// ---------- kernel 6: per-token absmax quantize h (fp16 input) ----------
__global__ void quant_h(const _Float16* __restrict__ H, int8_t* __restrict__ qh,
                        float* __restrict__ shinv) {
    const int row = blockIdx.x;
    const int t = threadIdx.x;
    const half8* h8 = (const half8*)(H + (size_t)row * D_HIDDEN) + t * 4;
    half8 v0 = h8[0], v1 = h8[1], v2 = h8[2], v3 = h8[3];
    float vals[32];
    #pragma unroll
    for (int i = 0; i < 8; ++i) {
        vals[i]      = (float)v0[i];
        vals[i + 8]  = (float)v1[i];
        vals[i + 16] = (float)v2[i];
        vals[i + 24] = (float)v3[i];
    }
    float m = 0.f;
    #pragma unroll
    for (int i = 0; i < 32; ++i) m = fmaxf(m, fabsf(vals[i]));
    for (int off = 32; off > 0; off >>= 1) m = fmaxf(m, __shfl_xor(m, off, 64));
    __shared__ float s[4];
    if ((t & 63) == 0) s[t >> 6] = m;
    __syncthreads();
    m = fmaxf(fmaxf(s[0], s[1]), fmaxf(s[2], s[3]));
    const float clipv = fmaxf(m, 1e-5f);
    const float scale = 127.0f / clipv;
    if (t == 0) shinv[row] = 1.0f / scale;
    union { char c[16]; int4 v; } u0, u1;
    #pragma unroll
    for (int i = 0; i < 16; ++i) {
        float qa = rintf(vals[i] * scale);
        qa = fminf(fmaxf(qa, -128.f), 127.f);
        u0.c[i] = (char)qa;
        float qb = rintf(vals[16 + i] * scale);
        qb = fminf(fmaxf(qb, -128.f), 127.f);
        u1.c[i] = (char)qb;
    }
    int4* dst = (int4*)(qh + (size_t)row * D_HIDDEN + t * 32);
    dst[0] = u0.v;
    dst[1] = u1.v;
}

// ---------- int8 MFMA GEMM: C[M,N] = A[M,K] * B[N,K]^T (both K-contiguous) ----------
// 32x32x32 i8 MFMA, 2x2 per wave (64x64 wave tile), 128x128 block, 4 waves.
// Double-buffered LDS, one barrier per 64-K step, XOR chunk swizzle on the
// global source (LDS dest of global_load_lds must stay lane-linear).
// __launch_bounds__(256,4): target 4 waves/EU (4 blocks/CU) — acc is 64 regs,
// frags 32, so <=128 total is feasible without spills.
// MODE 0: dequant + exact-erf GELU -> fp16 H ; MODE 1: dequant -> fp32 out
template <int MODE, int K, int N>
__global__ __launch_bounds__(256, 4) void gemm_i8(
    const int8_t* __restrict__ A, const int8_t* __restrict__ B,
    void* __restrict__ Cout, const float* __restrict__ rowinv,
    const float* __restrict__ wdeq) {
    __shared__ __align__(16) int8_t As[2][128 * 64];
    __shared__ __align__(16) int8_t Bs[2][128 * 64];
    const int tid = threadIdx.x;
    const int lane = tid & 63;
    const int wid = tid >> 6;
    const int row0 = blockIdx.y * 128;
    const int col0 = blockIdx.x * 128;
    const int wm = (wid >> 1) * 64;
    const int wn = (wid & 1) * 64;
    const int l31 = lane & 31;
    const int lh = lane >> 5;   // 0/1: which 16B k-chunk of the 32-K slice

    // staging: thread tid loads a 16B chunk -> LDS offset tid*16 (+4096 for rows 64..127)
    const int sm = tid >> 2;       // LDS row 0..63 (it0), +64 (it1)
    const int sc = tid & 3;        // physical chunk column
    const int swk = ((sc ^ ((sm >> 2) & 3)) << 4);  // swizzled k-offset in global row
    const int8_t* gA0 = A + (size_t)(row0 + sm) * K + swk;
    const int8_t* gA1 = gA0 + (size_t)64 * K;
    const int8_t* gB0 = B + (size_t)(col0 + sm) * K + swk;
    const int8_t* gB1 = gB0 + (size_t)64 * K;
    const int ldso = tid * 16;

#define STAGE(pA, pB, kk)                                                              \
    do {                                                                               \
        __builtin_amdgcn_global_load_lds(                                              \
            (const __attribute__((address_space(1))) void*)(gA0 + (kk)),               \
            (__attribute__((address_space(3))) void*)((pA) + ldso), 16, 0, 0);         \
        __builtin_amdgcn_global_load_lds(                                              \
            (const __attribute__((address_space(1))) void*)(gA1 + (kk)),               \
            (__attribute__((address_space(3))) void*)((pA) + ldso + 4096), 16, 0, 0);  \
        __builtin_amdgcn_global_load_lds(                                              \
            (const __attribute__((address_space(1))) void*)(gB0 + (kk)),               \
            (__attribute__((address_space(3))) void*)((pB) + ldso), 16, 0, 0);         \
        __builtin_amdgcn_global_load_lds(                                              \
            (const __attribute__((address_space(1))) void*)(gB1 + (kk)),               \
            (__attribute__((address_space(3))) void*)((pB) + ldso + 4096), 16, 0, 0);  \
    } while (0)

    // fragment read offsets: A[m=l31][k = lh*16 + j] per 32-K slice, XOR-swizzled.
    // LDS row = wm/wn + mi*32 + l31; swizzle key = (row>>2)&3 = (l31>>2)&3
    // (wm, mi*32 are multiples of 16 rows -> key depends only on l31).
    const int key = (l31 >> 2) & 3;
    int aoff[2][2], boff[2][2];
    #pragma unroll
    for (int mi = 0; mi < 2; ++mi)
        #pragma unroll
        for (int ks = 0; ks < 2; ++ks) {
            const int ch = ((lh + ks * 2) ^ key) << 4;
            aoff[mi][ks] = (wm + mi * 32 + l31) * 64 + ch;
            boff[mi][ks] = (wn + mi * 32 + l31) * 64 + ch;
        }

    v16i acc[2][2] = {};

#define COMPUTE(pA, pB)                                                                 \
    do {                                                                                \
        v4i a0 = *(const v4i*)((pA) + aoff[0][0]);                                      \
        v4i a1 = *(const v4i*)((pA) + aoff[1][0]);                                      \
        v4i b0 = *(const v4i*)((pB) + boff[0][0]);                                      \
        v4i b1 = *(const v4i*)((pB) + boff[1][0]);                                      \
        v4i a2 = *(const v4i*)((pA) + aoff[0][1]);                                      \
        v4i a3 = *(const v4i*)((pA) + aoff[1][1]);                                      \
        v4i b2 = *(const v4i*)((pB) + boff[0][1]);                                      \
        v4i b3 = *(const v4i*)((pB) + boff[1][1]);                                      \
        acc[0][0] = __builtin_amdgcn_mfma_i32_32x32x32_i8(a0, b0, acc[0][0], 0, 0, 0);  \
        acc[0][1] = __builtin_amdgcn_mfma_i32_32x32x32_i8(a0, b1, acc[0][1], 0, 0, 0);  \
        acc[1][0] = __builtin_amdgcn_mfma_i32_32x32x32_i8(a1, b0, acc[1][0], 0, 0, 0);  \
        acc[1][1] = __builtin_amdgcn_mfma_i32_32x32x32_i8(a1, b1, acc[1][1], 0, 0, 0);  \
        acc[0][0] = __builtin_amdgcn_mfma_i32_32x32x32_i8(a2, b2, acc[0][0], 0, 0, 0);  \
        acc[0][1] = __builtin_amdgcn_mfma_i32_32x32x32_i8(a2, b3, acc[0][1], 0, 0, 0);  \
        acc[1][0] = __builtin_amdgcn_mfma_i32_32x32x32_i8(a3, b2, acc[1][0], 0, 0, 0);  \
        acc[1][1] = __builtin_amdgcn_mfma_i32_32x32x32_i8(a3, b3, acc[1][1], 0, 0, 0);  \
    } while (0)

    STAGE(As[0], Bs[0], 0);
    for (int k0 = 0; k0 < K; k0 += 128) {
        __syncthreads();                               // drains tile k0 loads
        if (k0 + 64 < K) STAGE(As[1], Bs[1], k0 + 64); // prefetch, hidden by compute
        COMPUTE(As[0], Bs[0]);
        __syncthreads();                               // drains tile k0+64 loads
        if (k0 + 128 < K) STAGE(As[0], Bs[0], k0 + 128);
        COMPUTE(As[1], Bs[1]);
    }
#undef STAGE
#undef COMPUTE

    // C/D layout (32x32, HW-verified m74/m101): col = lane&31,
    // row = (reg&3) + 8*(reg>>2) + 4*(lane>>5)
    const float dw = *wdeq;
    #pragma unroll
    for (int mi = 0; mi < 2; ++mi) {
        #pragma unroll
        for (int reg = 0; reg < 16; ++reg) {
            const int crow = (reg & 3) + 8 * (reg >> 2) + 4 * lh;
            const int grow = row0 + wm + mi * 32 + crow;
            const float ri = rowinv[grow] * dw;
            #pragma unroll
            for (int ni = 0; ni < 2; ++ni) {
                const int gcol = col0 + wn + ni * 32 + l31;
                float v = (float)acc[mi][ni][reg] * ri;
                if (MODE == 0) {
                    float g = 0.5f * v * (1.0f + erff(v * 0.70710678118654752f));
                    ((_Float16*)Cout)[(size_t)grow * N + gcol] = (_Float16)g;
                } else {
                    ((float*)Cout)[(size_t)grow * N + gcol] = v;
                }
            }
        }
    }
}

extern "C" void kernel_launch(void* const* d_in, const int* in_sizes, int n_in,
                              void* d_out, int out_size, void* d_ws, size_t ws_size,
                              hipStream_t stream) {
    const float* x  = (const float*)d_in[0];
    const float* w1 = (const float*)d_in[1];
    const float* w2 = (const float*)d_in[2];
    float* out = (float*)d_out;
    char* ws = (char*)d_ws;

    int8_t*   qx   = (int8_t*)(ws + OFF_QX);
    int8_t*   qw1  = (int8_t*)(ws + OFF_QW1);
    int8_t*   qw2  = (int8_t*)(ws + OFF_QW2);
    int8_t*   qh   = (int8_t*)(ws + OFF_QH);
    _Float16* h    = (_Float16*)(ws + OFF_H);
    float*    sxi  = (float*)(ws + OFF_SXI);
    float*    shi  = (float*)(ws + OFF_SHI);
    float*    wpar = (float*)(ws + OFF_WP);
    double*   part = (double*)(ws + OFF_PART);

    wabs_partial<<<2048, 256, 0, stream>>>(w1, w2, part);
    wscale_final<<<1, 1024, 0, stream>>>(part, wpar);
    quant_w<<<32768, 256, 0, stream>>>(w1, w2, wpar, qw1, qw2);
    quant_x<<<NTOK, 256, 0, stream>>>(x, qx, sxi);
    gemm_i8<0, D_MODEL, D_HIDDEN><<<dim3(D_HIDDEN / 128, NTOK / 128), 256, 0, stream>>>(
        qx, qw1, (void*)h, sxi, wpar + 1);
    quant_h<<<NTOK, 256, 0, stream>>>(h, qh, shi);
    gemm_i8<1, D_HIDDEN, D_MODEL><<<dim3(D_MODEL / 128, NTOK / 128), 256, 0, stream>>>(
        qh, qw2, (void*)out, shi, wpar + 3);
}